// Round 1
// baseline (117.532 us; speedup 1.0000x reference)
//
#include <hip/hip_runtime.h>

#define T_STEPS 1000
#define BETA0   1e-4f
#define BETA1T  20.0f

// ---------------------------------------------------------------------------
// Kernel 1: build the 1001-entry lookup table exp(cumsum(log1p(-beta))).
// One block of 256 threads; each thread owns 4 consecutive steps.
// ---------------------------------------------------------------------------
__global__ void ddpm_build_table(float* __restrict__ table) {
    __shared__ float partial[256];
    const int tid = threadIdx.x;

    // Per-thread inclusive prefix over its 4 elements (s-1 = k in [0, 1000)).
    float vals[4];
    float local = 0.0f;
    #pragma unroll
    for (int j = 0; j < 4; ++j) {
        int k = tid * 4 + j;                 // k = s-1
        float v = 0.0f;
        if (k < T_STEPS) {
            float frac = (float)k / (float)(T_STEPS - 1);
            float beta = BETA0 * (1.0f - frac) + (BETA1T / (float)T_STEPS) * frac;
            v = log1pf(-beta);
        }
        local += v;
        vals[j] = local;                     // inclusive within the group of 4
    }
    partial[tid] = local;
    __syncthreads();

    // Hillis-Steele inclusive scan over the 256 per-thread sums.
    #pragma unroll
    for (int off = 1; off < 256; off <<= 1) {
        float add = (tid >= off) ? partial[tid - off] : 0.0f;
        __syncthreads();
        partial[tid] += add;
        __syncthreads();
    }
    float prefix = (tid > 0) ? partial[tid - 1] : 0.0f;

    if (tid == 0) table[0] = 1.0f;           // empty product
    #pragma unroll
    for (int j = 0; j < 4; ++j) {
        int k = tid * 4 + j;
        if (k < T_STEPS) table[k + 1] = expf(prefix + vals[j]);
    }
}

// ---------------------------------------------------------------------------
// Kernel 2: out[i] = table[clip(rint(t[i]), 0, 1000)]
// float4 vectorized; table staged in LDS per block.
// ---------------------------------------------------------------------------
__global__ __launch_bounds__(256)
void ddpm_gather(const float* __restrict__ t,
                 float* __restrict__ out,
                 const float* __restrict__ table,
                 int n) {
    __shared__ float lut[T_STEPS + 1];
    for (int i = threadIdx.x; i < T_STEPS + 1; i += blockDim.x)
        lut[i] = table[i];
    __syncthreads();

    const int gid = blockIdx.x * blockDim.x + threadIdx.x;
    const int n4  = n >> 2;

    if (gid < n4) {
        const float4* __restrict__ t4 = (const float4*)t;
        float4*       __restrict__ o4 = (float4*)out;
        float4 v = t4[gid];
        int i0 = (int)rintf(v.x); i0 = min(max(i0, 0), T_STEPS);
        int i1 = (int)rintf(v.y); i1 = min(max(i1, 0), T_STEPS);
        int i2 = (int)rintf(v.z); i2 = min(max(i2, 0), T_STEPS);
        int i3 = (int)rintf(v.w); i3 = min(max(i3, 0), T_STEPS);
        float4 r;
        r.x = lut[i0];
        r.y = lut[i1];
        r.z = lut[i2];
        r.w = lut[i3];
        o4[gid] = r;
    }

    // Tail (n not divisible by 4) — handled by the first few threads.
    int tail = n - (n4 << 2);
    if (gid < tail) {
        int k = (n4 << 2) + gid;
        int i = (int)rintf(t[k]); i = min(max(i, 0), T_STEPS);
        out[k] = lut[i];
    }
}

extern "C" void kernel_launch(void* const* d_in, const int* in_sizes, int n_in,
                              void* d_out, int out_size, void* d_ws, size_t ws_size,
                              hipStream_t stream) {
    const float* t = (const float*)d_in[0];
    float* out     = (float*)d_out;
    float* table   = (float*)d_ws;          // 1001 floats of scratch
    const int n    = in_sizes[0];

    ddpm_build_table<<<1, 256, 0, stream>>>(table);

    int n4     = n >> 2;
    int blocks = (n4 + 255) / 256;
    if (blocks < 1) blocks = 1;
    ddpm_gather<<<blocks, 256, 0, stream>>>(t, out, table, n);
}

// Round 2
// 108.969 us; speedup vs baseline: 1.0786x; 1.0786x over previous
//
#include <hip/hip_runtime.h>

// ---------------------------------------------------------------------------
// Closed form: beta_j = a + d*j (j = 0..999), a = 1e-4, d = (0.02-1e-4)/999.
// clog(k) = sum_{j<k} log1p(-beta_j)
//         = -(S1 + S2/2 + S3/3) + O(sum beta^4/4)   [truncation <= 8e-6]
// Power sums over j=0..k-1 give a degree-4 polynomial in k:
//   clog(k) = -k*(A1 + k*(A2 + k*(A3 + k*A4)))
// Coefficients computed in double at compile time.
// ---------------------------------------------------------------------------
namespace {
constexpr double a_  = 1e-4;
constexpr double d_  = (20.0 / 1000.0 - 1e-4) / 999.0;

// S1 = (a - d/2) k + (d/2) k^2
// S2 = (a^2 - a d + d^2/6) k + (a d - d^2/2) k^2 + (d^2/3) k^3
// S3 = (a^3 - 1.5 a^2 d + 0.5 a d^2) k + (1.5 a^2 d - 1.5 a d^2 + 0.25 d^3) k^2
//      + (a d^2 - 0.5 d^3) k^3 + (d^3/4) k^4
constexpr double A1d = (a_ - d_ / 2.0)
                     + (a_ * a_ - a_ * d_ + d_ * d_ / 6.0) / 2.0
                     + (a_ * a_ * a_ - 1.5 * a_ * a_ * d_ + 0.5 * a_ * d_ * d_) / 3.0;
constexpr double A2d = d_ / 2.0
                     + (a_ * d_ - d_ * d_ / 2.0) / 2.0
                     + (1.5 * a_ * a_ * d_ - 1.5 * a_ * d_ * d_ + 0.25 * d_ * d_ * d_) / 3.0;
constexpr double A3d = d_ * d_ / 6.0
                     + (a_ * d_ * d_ - 0.5 * d_ * d_ * d_) / 3.0;
constexpr double A4d = d_ * d_ * d_ / 12.0;

constexpr float A1 = (float)A1d;
constexpr float A2 = (float)A2d;
constexpr float A3 = (float)A3d;
constexpr float A4 = (float)A4d;
constexpr float LOG2E = 1.4426950408889634f;
}

__device__ __forceinline__ float alpha_bar(float v) {
    // k = clip(round(v), 0, 1000), kept in float (rndne = round-half-even,
    // matching jnp.round).
    float k = __builtin_rintf(v);
    k = fminf(fmaxf(k, 0.0f), 1000.0f);
    // clog(k) via Horner, then exp(clog) = exp2(clog * log2(e)).
    float p = fmaf(k, A4, A3);
    p = fmaf(k, p, A2);
    p = fmaf(k, p, A1);
    float clog = -k * p;
    return exp2f(clog * LOG2E);
}

__global__ __launch_bounds__(256)
void ddpm_alpha_bar(const float* __restrict__ t,
                    float* __restrict__ out,
                    int n) {
    const int gid = blockIdx.x * blockDim.x + threadIdx.x;
    const int n4  = n >> 2;

    if (gid < n4) {
        float4 v = ((const float4*)t)[gid];
        float4 r;
        r.x = alpha_bar(v.x);
        r.y = alpha_bar(v.y);
        r.z = alpha_bar(v.z);
        r.w = alpha_bar(v.w);
        ((float4*)out)[gid] = r;
    }

    // Tail (n not divisible by 4).
    int tail = n - (n4 << 2);
    if (gid < tail) {
        int k = (n4 << 2) + gid;
        out[k] = alpha_bar(t[k]);
    }
}

extern "C" void kernel_launch(void* const* d_in, const int* in_sizes, int n_in,
                              void* d_out, int out_size, void* d_ws, size_t ws_size,
                              hipStream_t stream) {
    const float* t = (const float*)d_in[0];
    float* out     = (float*)d_out;
    const int n    = in_sizes[0];

    int n4     = (n + 3) >> 2;
    int blocks = (n4 + 255) / 256;
    if (blocks < 1) blocks = 1;
    ddpm_alpha_bar<<<blocks, 256, 0, stream>>>(t, out, n);
}